// Round 7
// baseline (183.683 us; speedup 1.0000x reference)
//
#include <hip/hip_runtime.h>
#include <math.h>

#define NB   4
#define CIN  512
#define HID  64
#define NK   11     // NUM_CLASSES+1
#define H1   60
#define W1p  80
#define P1   4800
#define H2   30
#define W2p  40
#define P2   1200
#define HO   480
#define WOp  640
#define NP1  (NB*P1)    // 19200
#define NP2  (NB*P2)    // 4800
#define PLANE ((size_t)HO*WOp)                  // 307200
#define SEG_OFF ((size_t)NB*NK*PLANE)           // 13,516,800
#define BBX_OFF (SEG_OFF + (size_t)NB*PLANE)    // 14,745,600

// ws layout in floats (proven size in rounds 1-2)
#define WS_WT1 0
#define WS_WT2 32768
#define WS_C1  65536                            // 19200*64 = 1,228,800
#define WS_F2  (WS_C1 + NP1*64)                 // 4800*64  =   307,200
#define WS_PRB (WS_F2 + NP2*64)                 // 19200*12 =   230,400
#define WS_SEG (WS_PRB + NP1*12)                // 19200 ints

// ---------------- transpose weights: wT[c*64+o] = w[o*512+c] ----------------
__global__ __launch_bounds__(256) void transpose_w(const float* __restrict__ w1,
                                                   const float* __restrict__ w2,
                                                   float* __restrict__ ws) {
    int i = blockIdx.x * 256 + threadIdx.x;   // 0..32767
    if (i >= HID * CIN) return;
    int o = i >> 9;           // /512
    int c = i & 511;
    ws[WS_WT1 + c * HID + o] = w1[i];
    ws[WS_WT2 + c * HID + o] = w2[i];
}

// ---------------- conv1x1, LDS-staged X, no redundancy, fused bias+relu -----
// 376 blocks x 512 thr (8 waves). Block = 64-px tile, ALL 64 rows, ALL 512 ch.
// X staged in LDS in 64-ch chunks (16KB, double-buffered, reg-staged): each X
// element fetched from global EXACTLY once, then read 8x from LDS (previous
// rounds fetched X 4x through L2/L3 -> ~190MB at ~5TB/s = the 40us stall).
// Wave w computes rows 8w..8w+7 for all 64 px (lane=px), acc[8].
// Weights: wave-uniform reads (readfirstlane'd row base) -> scalar cache.
__global__ __launch_bounds__(512) void conv_fused(const float* __restrict__ f1,
                                                  const float* __restrict__ f2,
                                                  const float* __restrict__ wt1,
                                                  const float* __restrict__ wt2,
                                                  const float* __restrict__ b1v,
                                                  const float* __restrict__ b2v,
                                                  float* __restrict__ c1o,
                                                  float* __restrict__ f2o) {
    __shared__ float xbuf[2][64][68];   // [buf][ch-in-chunk][px], +4 pad: writes <=2-way
    int t = blockIdx.x;
    const float* X; const float* wT; const float* bias; float* Cout;
    int P, px0;
    if (t < 300) {
        int b = t / 75; px0 = (t % 75) * 64;
        X = f1 + (size_t)b * CIN * P1;  P = P1;  wT = wt1;  bias = b1v;
        Cout = c1o + (size_t)b * P1 * 64;
    } else {
        int u = t - 300; int b = u / 19; int ti = u % 19;
        px0 = ti * 64; if (px0 > P2 - 64) px0 = P2 - 64;   // overlap tail tile (benign dup stores)
        X = f2 + (size_t)b * CIN * P2;  P = P2;  wT = wt2;  bias = b2v;
        Cout = f2o + (size_t)b * P2 * 64;
    }
    int tid  = threadIdx.x;
    int lane = tid & 63;
    int wv   = tid >> 6;                                   // 0..7
    int row0 = __builtin_amdgcn_readfirstlane(wv << 3);    // 8*wave -> SGPR
    // staging coords: thread owns 32B of one channel row
    int sc = tid >> 3;            // channel-in-chunk 0..63
    int sq = (tid & 7) * 8;       // px offset 0,8,..,56
    const float* gsrc = X + (size_t)sc * P + px0 + sq;

    float acc[8];
#pragma unroll
    for (int r = 0; r < 8; ++r) acc[r] = 0.f;

    // prologue: stage chunk 0
    {
        float4 ra = *(const float4*)(gsrc);
        float4 rb = *(const float4*)(gsrc + 4);
        *(float4*)&xbuf[0][sc][sq]     = ra;
        *(float4*)&xbuf[0][sc][sq + 4] = rb;
    }
    __syncthreads();

    int cur = 0;
    for (int ch = 0; ch < 8; ++ch) {
        float4 na, nb;
        if (ch < 7) {   // issue next-chunk loads early (latency hides under compute)
            const float* g = gsrc + (size_t)(ch + 1) * 64 * P;
            na = *(const float4*)(g);
            nb = *(const float4*)(g + 4);
        }
        const float* wp = wT + (size_t)(ch * 64) * 64 + row0;   // uniform
#pragma unroll
        for (int c = 0; c < 64; ++c) {
            float x = xbuf[cur][c][lane];
            float4 w0 = *(const float4*)(wp);
            float4 w1 = *(const float4*)(wp + 4);
            acc[0] = fmaf(x, w0.x, acc[0]);
            acc[1] = fmaf(x, w0.y, acc[1]);
            acc[2] = fmaf(x, w0.z, acc[2]);
            acc[3] = fmaf(x, w0.w, acc[3]);
            acc[4] = fmaf(x, w1.x, acc[4]);
            acc[5] = fmaf(x, w1.y, acc[5]);
            acc[6] = fmaf(x, w1.z, acc[6]);
            acc[7] = fmaf(x, w1.w, acc[7]);
            wp += 64;
        }
        if (ch < 7) {
            *(float4*)&xbuf[cur ^ 1][sc][sq]     = na;
            *(float4*)&xbuf[cur ^ 1][sc][sq + 4] = nb;
        }
        __syncthreads();
        cur ^= 1;
    }

    // epilogue: bias + relu + store final (px-major [p][64])
    float v[8];
#pragma unroll
    for (int r = 0; r < 8; ++r) {
        float a = acc[r] + bias[row0 + r];
        v[r] = a > 0.f ? a : 0.f;
    }
    float* op = Cout + (size_t)(px0 + lane) * 64 + row0;
    *(float4*)(op)     = make_float4(v[0], v[1], v[2], v[3]);
    *(float4*)(op + 4) = make_float4(v[4], v[5], v[6], v[7]);
}

// ---------------- head: add feat2-up, wo conv, softmax, argmax -> prb/seg ---
__global__ __launch_bounds__(256) void head_kernel(const float* __restrict__ wo,
                                                   const float* __restrict__ bo,
                                                   float* __restrict__ ws) {
    __shared__ float swo[NK * 64];
    __shared__ float sbo[NK];
    for (int i = threadIdx.x; i < NK * 64; i += 256) swo[i] = wo[i];
    if (threadIdx.x < NK) sbo[threadIdx.x] = bo[threadIdx.x];
    __syncthreads();

    int p  = blockIdx.x * 256 + threadIdx.x;   // 0..19199
    int b  = p / P1;
    int pb = p % P1;
    int y  = pb / W1p, x = pb % W1p;
    int qp = (y >> 1) * W2p + (x >> 1);
    const float* c1p = ws + WS_C1 + ((size_t)b * P1 + pb) * 64;
    const float* f2p = ws + WS_F2 + ((size_t)b * P2 + qp) * 64;

    float ok[NK];
#pragma unroll
    for (int k = 0; k < NK; ++k) ok[k] = sbo[k];
#pragma unroll
    for (int o4 = 0; o4 < 16; ++o4) {
        float4 c1q = *(const float4*)(c1p + o4 * 4);
        float4 f2q = *(const float4*)(f2p + o4 * 4);
        float co[4] = { c1q.x + f2q.x, c1q.y + f2q.y, c1q.z + f2q.z, c1q.w + f2q.w };
#pragma unroll
        for (int j = 0; j < 4; ++j) {
            int o = o4 * 4 + j;
#pragma unroll
            for (int k = 0; k < NK; ++k) ok[k] = fmaf(co[j], swo[k * 64 + o], ok[k]);
        }
    }
    float m = 0.f;
#pragma unroll
    for (int k = 0; k < NK; ++k) {
        ok[k] = ok[k] > 0.f ? ok[k] : 0.f;          // relu(out)
        if (ok[k] > m) m = ok[k];
    }
    float e[NK], sum = 0.f;
#pragma unroll
    for (int k = 0; k < NK; ++k) { e[k] = expf(ok[k] - m); sum += e[k]; }
    float inv = 1.f / sum;
    int arg = 0; float best = ok[0];
#pragma unroll
    for (int k = 1; k < NK; ++k) { if (ok[k] > best) { best = ok[k]; arg = k; } }

    float* pr = ws + WS_PRB + (size_t)p * 12;
#pragma unroll
    for (int k = 0; k < NK; ++k) pr[k] = e[k] * inv;
    pr[11] = (float)arg;
    ((int*)(ws + WS_SEG))[p] = arg;
}

// ---------------- upsample 8x: pure streaming replicate-store ----------------
__global__ __launch_bounds__(256) void upsample_kernel(const float* __restrict__ ws,
                                                       float* __restrict__ out) {
    const float* prb = ws + WS_PRB;
    unsigned total4 = (unsigned)((SEG_OFF + (size_t)NB * PLANE) / 4);  // 3,686,400
    unsigned step = gridDim.x * 256;
    for (unsigned i4 = blockIdx.x * 256 + threadIdx.x; i4 < total4; i4 += step) {
        unsigned f = i4 * 4;
        float v;
        if (f < (unsigned)SEG_OFF) {
            unsigned plane = f / (unsigned)PLANE;      // 0..43
            unsigned r = f - plane * (unsigned)PLANE;
            unsigned b = plane / NK, k = plane - b * NK;
            unsigned y = r / WOp, x = r - y * WOp;
            unsigned p = b * P1 + (y >> 3) * W1p + (x >> 3);
            v = prb[p * 12 + k];
        } else {
            unsigned g = f - (unsigned)SEG_OFF;
            unsigned b = g / (unsigned)PLANE;
            unsigned r = g - b * (unsigned)PLANE;
            unsigned y = r / WOp, x = r - y * WOp;
            unsigned p = b * P1 + (y >> 3) * W1p + (x >> 3);
            v = prb[p * 12 + 11];
        }
        *(float4*)(out + f) = make_float4(v, v, v, v);
    }
}

// ---------------- bbox: per-(batch,class) min/max/count over 60x80 seg ------
__global__ __launch_bounds__(256) void bbx_kernel(const float* __restrict__ ws,
                                                  float* __restrict__ out) {
    __shared__ int cnt[10], xmn[10], xmx[10], ymn[10], ymx[10];
    int b = blockIdx.x;
    int t = threadIdx.x;
    if (t < 10) { cnt[t] = 0; xmn[t] = 1 << 30; xmx[t] = -1; ymn[t] = 1 << 30; ymx[t] = -1; }
    __syncthreads();
    const int* seg = (const int*)(ws + WS_SEG) + b * P1;
    for (int p = t; p < P1; p += 256) {
        int s = seg[p];
        if (s >= 1 && s <= 9) {
            int y = p / W1p, x = p % W1p;
            atomicAdd(&cnt[s], 1);
            atomicMin(&xmn[s], x); atomicMax(&xmx[s], x);
            atomicMin(&ymn[s], y); atomicMax(&ymx[s], y);
        }
    }
    __syncthreads();
    if (t < 9) {
        int c = t + 1;
        bool valid = cnt[c] * 64 >= 500;    // upsampled count = 64*count
        float r[6];
        if (valid) {
            r[0] = (float)b;
            r[1] = (float)(xmn[c] * 8);
            r[2] = (float)(ymn[c] * 8);
            r[3] = (float)(xmx[c] * 8 + 7);
            r[4] = (float)(ymx[c] * 8 + 7);
            r[5] = (float)c;
        } else {
            for (int i = 0; i < 6; ++i) r[i] = -1.f;
        }
        float* row = out + BBX_OFF + (size_t)(b * 9 + t) * 6;
        for (int i = 0; i < 6; ++i) row[i] = r[i];
    }
}

extern "C" void kernel_launch(void* const* d_in, const int* in_sizes, int n_in,
                              void* d_out, int out_size, void* d_ws, size_t ws_size,
                              hipStream_t stream) {
    const float* f1 = (const float*)d_in[0];
    const float* f2 = (const float*)d_in[1];
    const float* w1 = (const float*)d_in[2];
    const float* b1 = (const float*)d_in[3];
    const float* w2 = (const float*)d_in[4];
    const float* b2 = (const float*)d_in[5];
    const float* wo = (const float*)d_in[6];
    const float* bo = (const float*)d_in[7];
    float* ws  = (float*)d_ws;
    float* out = (float*)d_out;

    transpose_w<<<128, 256, 0, stream>>>(w1, w2, ws);
    conv_fused<<<376, 512, 0, stream>>>(f1, f2, ws + WS_WT1, ws + WS_WT2,
                                        b1, b2, ws + WS_C1, ws + WS_F2);
    head_kernel<<<75, 256, 0, stream>>>(wo, bo, ws);
    upsample_kernel<<<2048, 256, 0, stream>>>(ws, out);
    bbx_kernel<<<NB, 256, 0, stream>>>(ws, out);
}

// Round 8
// 72.750 us; speedup vs baseline: 2.5249x; 2.5249x over previous
//
#include <hip/hip_runtime.h>
#include <math.h>

#define NB   4
#define CIN  512
#define HID  64
#define NK   11     // NUM_CLASSES+1
#define H1   60
#define W1p  80
#define P1   4800
#define H2   30
#define W2p  40
#define P2   1200
#define HO   480
#define WOp  640
#define NP1  (NB*P1)    // 19200
#define NP2  (NB*P2)    // 4800
#define PLANE ((size_t)HO*WOp)                  // 307200
#define SEG_OFF ((size_t)NB*NK*PLANE)           // 13,516,800
#define BBX_OFF (SEG_OFF + (size_t)NB*PLANE)    // 14,745,600

// ws layout in floats
#define WS_WT1 0
#define WS_WT2 32768
#define WS_C1  65536                            // 19200*64 = 1,228,800
#define WS_F2  (WS_C1 + NP1*64)                 // 4800*64  =   307,200
#define WS_PRB (WS_F2 + NP2*64)                 // 19200*12 =   230,400
#define WS_SEG (WS_PRB + NP1*12)                // 19200 ints

// ---------------- transpose weights: wT[c*64+o] = w[o*512+c] ----------------
__global__ __launch_bounds__(256) void transpose_w(const float* __restrict__ w1,
                                                   const float* __restrict__ w2,
                                                   float* __restrict__ ws) {
    int i = blockIdx.x * 256 + threadIdx.x;   // 0..32767
    if (i >= HID * CIN) return;
    int o = i >> 9;           // /512
    int c = i & 511;
    ws[WS_WT1 + c * HID + o] = w1[i];
    ws[WS_WT2 + c * HID + o] = w2[i];
}

// ---------------- conv1x1: K-sliced waves, scalar weights, LDS tree-reduce --
// 376 blocks x 512 thr (8 waves). Block = 64-px tile, ALL 64 rows, ALL 512 ch.
// Wave w owns DISJOINT channels 64w..64w+63 -> X read EXACTLY once grid-wide
// (49MB, ~8us HBM floor). Lane = pixel: x loads coalesced 256B/wave-inst,
// 8-deep double buffer. acc[64]: 64 FMA insts per x-load (128cy VALU per VMEM
// op) -- fixes r7's 8:1 ratio collapse. Weights: readfirstlane-uniform pointer
// -> s_load via K$ (16 dwords/ch, no VMEM/LDS issue slots). Epilogue: 3-round
// LDS tree reduce of the 8 K-slices ([r][lane] b32 = conflict-free), bias+relu.
// 3008 waves (~3/SIMD), ~95 VGPR -> 2 blocks/CU co-resident.
__global__ __launch_bounds__(512, 4) void conv_sg(const float* __restrict__ f1,
                                                  const float* __restrict__ f2,
                                                  const float* __restrict__ wt1,
                                                  const float* __restrict__ wt2,
                                                  const float* __restrict__ b1v,
                                                  const float* __restrict__ b2v,
                                                  float* __restrict__ c1o,
                                                  float* __restrict__ f2o) {
    __shared__ float rbuf[4][64][64];   // 64KB tree-reduce buffers
    int t = blockIdx.x;
    const float* X; const float* wT; const float* bias; float* Cout;
    int P, px0;
    if (t < 300) {
        int b = t / 75; px0 = (t % 75) * 64;
        X = f1 + (size_t)b * CIN * P1;  P = P1;  wT = wt1;  bias = b1v;
        Cout = c1o + (size_t)b * P1 * 64;
    } else {
        int u = t - 300; int b = u / 19; int ti = u % 19;
        px0 = ti * 64; if (px0 > P2 - 64) px0 = P2 - 64;  // tail overlap: dup stores benign
        X = f2 + (size_t)b * CIN * P2;  P = P2;  wT = wt2;  bias = b2v;
        Cout = f2o + (size_t)b * P2 * 64;
    }
    int lane  = threadIdx.x & 63;
    int wv    = threadIdx.x >> 6;                               // 0..7
    int cbase = __builtin_amdgcn_readfirstlane(wv << 6);        // 64*wave (SGPR)

    const float* Xp = X + (size_t)cbase * P + px0 + lane;
    const float* Wp = wT + (size_t)cbase * 64;                  // uniform -> s_load

    float acc[64];
#pragma unroll
    for (int r = 0; r < 64; ++r) acc[r] = 0.f;

    float xa[8], xn[8];
#pragma unroll
    for (int i = 0; i < 8; ++i) xa[i] = Xp[(size_t)i * P];

    for (int c0 = 0; c0 < 64; c0 += 8) {
        if (c0 < 56) {
#pragma unroll
            for (int i = 0; i < 8; ++i) xn[i] = Xp[(size_t)(c0 + 8 + i) * P];
        }
#pragma unroll
        for (int i = 0; i < 8; ++i) {
            const float* wr = Wp + (size_t)(c0 + i) * 64;       // uniform address
            float x = xa[i];
#pragma unroll
            for (int r4 = 0; r4 < 16; ++r4) {
                float4 w = *(const float4*)(wr + r4 * 4);
                acc[r4*4+0] = fmaf(x, w.x, acc[r4*4+0]);
                acc[r4*4+1] = fmaf(x, w.y, acc[r4*4+1]);
                acc[r4*4+2] = fmaf(x, w.z, acc[r4*4+2]);
                acc[r4*4+3] = fmaf(x, w.w, acc[r4*4+3]);
            }
        }
#pragma unroll
        for (int i = 0; i < 8; ++i) xa[i] = xn[i];
    }

    // tree reduce: 8 -> 4 -> 2 -> 1 (rbuf[.][r][lane]: lane-consecutive, conflict-free)
    if (wv >= 4) {
#pragma unroll
        for (int r = 0; r < 64; ++r) rbuf[wv - 4][r][lane] = acc[r];
    }
    __syncthreads();
    if (wv < 4) {
#pragma unroll
        for (int r = 0; r < 64; ++r) acc[r] += rbuf[wv][r][lane];
    }
    __syncthreads();
    if (wv == 2 || wv == 3) {
#pragma unroll
        for (int r = 0; r < 64; ++r) rbuf[wv - 2][r][lane] = acc[r];
    }
    __syncthreads();
    if (wv < 2) {
#pragma unroll
        for (int r = 0; r < 64; ++r) acc[r] += rbuf[wv][r][lane];
    }
    __syncthreads();
    if (wv == 1) {
#pragma unroll
        for (int r = 0; r < 64; ++r) rbuf[0][r][lane] = acc[r];
    }
    __syncthreads();
    if (wv == 0) {
        float* op = Cout + (size_t)(px0 + lane) * 64;
#pragma unroll
        for (int r4 = 0; r4 < 16; ++r4) {
            float v[4];
#pragma unroll
            for (int j = 0; j < 4; ++j) {
                int r = r4 * 4 + j;
                float a = acc[r] + rbuf[0][r][lane] + bias[r];
                v[j] = a > 0.f ? a : 0.f;
            }
            *(float4*)(op + r4 * 4) = make_float4(v[0], v[1], v[2], v[3]);
        }
    }
}

// ---------------- head: add feat2-up, wo conv, softmax, argmax -> prb/seg ---
__global__ __launch_bounds__(256) void head_kernel(const float* __restrict__ wo,
                                                   const float* __restrict__ bo,
                                                   float* __restrict__ ws) {
    __shared__ float swo[NK * 64];
    __shared__ float sbo[NK];
    for (int i = threadIdx.x; i < NK * 64; i += 256) swo[i] = wo[i];
    if (threadIdx.x < NK) sbo[threadIdx.x] = bo[threadIdx.x];
    __syncthreads();

    int p  = blockIdx.x * 256 + threadIdx.x;   // 0..19199
    int b  = p / P1;
    int pb = p % P1;
    int y  = pb / W1p, x = pb % W1p;
    int qp = (y >> 1) * W2p + (x >> 1);
    const float* c1p = ws + WS_C1 + ((size_t)b * P1 + pb) * 64;
    const float* f2p = ws + WS_F2 + ((size_t)b * P2 + qp) * 64;

    float ok[NK];
#pragma unroll
    for (int k = 0; k < NK; ++k) ok[k] = sbo[k];
#pragma unroll
    for (int o4 = 0; o4 < 16; ++o4) {
        float4 c1q = *(const float4*)(c1p + o4 * 4);
        float4 f2q = *(const float4*)(f2p + o4 * 4);
        float co[4] = { c1q.x + f2q.x, c1q.y + f2q.y, c1q.z + f2q.z, c1q.w + f2q.w };
#pragma unroll
        for (int j = 0; j < 4; ++j) {
            int o = o4 * 4 + j;
#pragma unroll
            for (int k = 0; k < NK; ++k) ok[k] = fmaf(co[j], swo[k * 64 + o], ok[k]);
        }
    }
    float m = 0.f;
#pragma unroll
    for (int k = 0; k < NK; ++k) {
        ok[k] = ok[k] > 0.f ? ok[k] : 0.f;          // relu(out)
        if (ok[k] > m) m = ok[k];
    }
    float e[NK], sum = 0.f;
#pragma unroll
    for (int k = 0; k < NK; ++k) { e[k] = expf(ok[k] - m); sum += e[k]; }
    float inv = 1.f / sum;
    int arg = 0; float best = ok[0];
#pragma unroll
    for (int k = 1; k < NK; ++k) { if (ok[k] > best) { best = ok[k]; arg = k; } }

    float* pr = ws + WS_PRB + (size_t)p * 12;
#pragma unroll
    for (int k = 0; k < NK; ++k) pr[k] = e[k] * inv;
    pr[11] = (float)arg;
    ((int*)(ws + WS_SEG))[p] = arg;
}

// ---------------- upsample 8x: pure streaming replicate-store ----------------
__global__ __launch_bounds__(256) void upsample_kernel(const float* __restrict__ ws,
                                                       float* __restrict__ out) {
    const float* prb = ws + WS_PRB;
    unsigned total4 = (unsigned)((SEG_OFF + (size_t)NB * PLANE) / 4);  // 3,686,400
    unsigned step = gridDim.x * 256;
    for (unsigned i4 = blockIdx.x * 256 + threadIdx.x; i4 < total4; i4 += step) {
        unsigned f = i4 * 4;
        float v;
        if (f < (unsigned)SEG_OFF) {
            unsigned plane = f / (unsigned)PLANE;      // 0..43
            unsigned r = f - plane * (unsigned)PLANE;
            unsigned b = plane / NK, k = plane - b * NK;
            unsigned y = r / WOp, x = r - y * WOp;
            unsigned p = b * P1 + (y >> 3) * W1p + (x >> 3);
            v = prb[p * 12 + k];
        } else {
            unsigned g = f - (unsigned)SEG_OFF;
            unsigned b = g / (unsigned)PLANE;
            unsigned r = g - b * (unsigned)PLANE;
            unsigned y = r / WOp, x = r - y * WOp;
            unsigned p = b * P1 + (y >> 3) * W1p + (x >> 3);
            v = prb[p * 12 + 11];
        }
        *(float4*)(out + f) = make_float4(v, v, v, v);
    }
}

// ---------------- bbox: per-(batch,class) min/max/count over 60x80 seg ------
__global__ __launch_bounds__(256) void bbx_kernel(const float* __restrict__ ws,
                                                  float* __restrict__ out) {
    __shared__ int cnt[10], xmn[10], xmx[10], ymn[10], ymx[10];
    int b = blockIdx.x;
    int t = threadIdx.x;
    if (t < 10) { cnt[t] = 0; xmn[t] = 1 << 30; xmx[t] = -1; ymn[t] = 1 << 30; ymx[t] = -1; }
    __syncthreads();
    const int* seg = (const int*)(ws + WS_SEG) + b * P1;
    for (int p = t; p < P1; p += 256) {
        int s = seg[p];
        if (s >= 1 && s <= 9) {
            int y = p / W1p, x = p % W1p;
            atomicAdd(&cnt[s], 1);
            atomicMin(&xmn[s], x); atomicMax(&xmx[s], x);
            atomicMin(&ymn[s], y); atomicMax(&ymx[s], y);
        }
    }
    __syncthreads();
    if (t < 9) {
        int c = t + 1;
        bool valid = cnt[c] * 64 >= 500;    // upsampled count = 64*count
        float r[6];
        if (valid) {
            r[0] = (float)b;
            r[1] = (float)(xmn[c] * 8);
            r[2] = (float)(ymn[c] * 8);
            r[3] = (float)(xmx[c] * 8 + 7);
            r[4] = (float)(ymx[c] * 8 + 7);
            r[5] = (float)c;
        } else {
            for (int i = 0; i < 6; ++i) r[i] = -1.f;
        }
        float* row = out + BBX_OFF + (size_t)(b * 9 + t) * 6;
        for (int i = 0; i < 6; ++i) row[i] = r[i];
    }
}

extern "C" void kernel_launch(void* const* d_in, const int* in_sizes, int n_in,
                              void* d_out, int out_size, void* d_ws, size_t ws_size,
                              hipStream_t stream) {
    const float* f1 = (const float*)d_in[0];
    const float* f2 = (const float*)d_in[1];
    const float* w1 = (const float*)d_in[2];
    const float* b1 = (const float*)d_in[3];
    const float* w2 = (const float*)d_in[4];
    const float* b2 = (const float*)d_in[5];
    const float* wo = (const float*)d_in[6];
    const float* bo = (const float*)d_in[7];
    float* ws  = (float*)d_ws;
    float* out = (float*)d_out;

    transpose_w<<<128, 256, 0, stream>>>(w1, w2, ws);
    conv_sg<<<376, 512, 0, stream>>>(f1, f2, ws + WS_WT1, ws + WS_WT2,
                                     b1, b2, ws + WS_C1, ws + WS_F2);
    head_kernel<<<75, 256, 0, stream>>>(wo, bo, ws);
    upsample_kernel<<<2048, 256, 0, stream>>>(ws, out);
    bbx_kernel<<<NB, 256, 0, stream>>>(ws, out);
}

// Round 9
// 68.345 us; speedup vs baseline: 2.6876x; 1.0645x over previous
//
#include <hip/hip_runtime.h>
#include <math.h>

#define NB   4
#define CIN  512
#define HID  64
#define NK   11     // NUM_CLASSES+1
#define H1   60
#define W1p  80
#define P1   4800
#define H2   30
#define W2p  40
#define P2   1200
#define HO   480
#define WOp  640
#define NP1  (NB*P1)    // 19200
#define NP2  (NB*P2)    // 4800
#define PLANE ((size_t)HO*WOp)                  // 307200
#define SEG_OFF ((size_t)NB*NK*PLANE)           // 13,516,800
#define BBX_OFF (SEG_OFF + (size_t)NB*PLANE)    // 14,745,600

// ws layout in floats
#define WS_WT1 0
#define WS_WT2 32768
#define WS_C1  65536                            // 19200*64 = 1,228,800
#define WS_F2  (WS_C1 + NP1*64)                 // 4800*64  =   307,200
#define WS_PRB (WS_F2 + NP2*64)                 // 19200*12 =   230,400
#define WS_SEG (WS_PRB + NP1*12)                // 19200 ints

// ---------------- transpose weights: wT[c*64+o] = w[o*512+c] ----------------
__global__ __launch_bounds__(256) void transpose_w(const float* __restrict__ w1,
                                                   const float* __restrict__ w2,
                                                   float* __restrict__ ws) {
    int i = blockIdx.x * 256 + threadIdx.x;   // 0..32767
    if (i >= HID * CIN) return;
    int o = i >> 9;           // /512
    int c = i & 511;
    ws[WS_WT1 + c * HID + o] = w1[i];
    ws[WS_WT2 + c * HID + o] = w2[i];
}

// ---------------- conv1x1: 4px/lane, K-quarter waves, scalar weights --------
// Diagnosis r2/r4/r8: conv wall pinned at ~40-47us == 48MB of weight dwords
// through the scalar path at ~1.1 TB/s (1 dword per FMA inst). Fix: lane owns
// 4 pixels (float4 x) so each weight SGPR dword feeds 4 FMA insts -> 12MB
// scalar traffic (~11us), overlapped with the 10us FMA floor.
// 384 blocks x 256 thr: block = (tile 256px, row-group rg 0..3); 4 waves =
// K-quarters (128ch each, disjoint -> X once per block). acc[16][4].
// rg-siblings re-read X 4x -> chunked XCD swizzle (384=8x48, bijective) puts
// consecutive logical blocks on one XCD so the refetch is L2-served.
// LDS: 3x16x256 f32 = 48KB reduce buffers (float4 rows, conflict-free).
__global__ __launch_bounds__(256) void conv_krg(const float* __restrict__ f1,
                                                const float* __restrict__ f2,
                                                const float* __restrict__ wt1,
                                                const float* __restrict__ wt2,
                                                const float* __restrict__ b1v,
                                                const float* __restrict__ b2v,
                                                float* __restrict__ c1o,
                                                float* __restrict__ f2o) {
    __shared__ float red[3][16][256];
    int D = blockIdx.x;                         // dispatch id
    int L = (D & 7) * 48 + (D >> 3);            // logical id: consecutive L share an XCD
    int tile = L >> 2;
    int rg   = L & 3;
    const float* X; const float* wT; const float* bias; float* Cout;
    int P, px0;
    if (tile < 76) {                            // f1: 4 batches x 19 tiles
        int b = tile / 19; int ti = tile % 19;
        px0 = ti * 256; if (px0 > P1 - 256) px0 = P1 - 256;  // overlap tail: dup stores benign
        X = f1 + (size_t)b * CIN * P1;  P = P1;  wT = wt1;  bias = b1v;
        Cout = c1o + (size_t)b * P1 * 64;
    } else {                                    // f2: 4 batches x 5 tiles
        int u = tile - 76; int b = u / 5; int ti = u % 5;
        px0 = ti * 256; if (px0 > P2 - 256) px0 = P2 - 256;
        X = f2 + (size_t)b * CIN * P2;  P = P2;  wT = wt2;  bias = b2v;
        Cout = f2o + (size_t)b * P2 * 64;
    }
    int lane  = threadIdx.x & 63;
    int kq    = threadIdx.x >> 6;                               // 0..3
    int cbase = __builtin_amdgcn_readfirstlane(kq << 7);        // 128*kq (SGPR)
    int row0  = rg << 4;                                        // uniform

    const float* Xp = X + (size_t)cbase * P + px0 + lane * 4;
    const float* Wp = wT + (size_t)cbase * 64 + row0;           // uniform -> s_load

    float acc[16][4];
#pragma unroll
    for (int r = 0; r < 16; ++r)
#pragma unroll
        for (int q = 0; q < 4; ++q) acc[r][q] = 0.f;

    float4 xa[4], xn[4];
#pragma unroll
    for (int i = 0; i < 4; ++i) xa[i] = *(const float4*)(Xp + (size_t)i * P);

    for (int c0 = 0; c0 < 128; c0 += 4) {
        if (c0 < 124) {
#pragma unroll
            for (int i = 0; i < 4; ++i)
                xn[i] = *(const float4*)(Xp + (size_t)(c0 + 4 + i) * P);
        }
#pragma unroll
        for (int i = 0; i < 4; ++i) {
            const float* wr = Wp + (size_t)(c0 + i) * 64;       // uniform address
            float4 x = xa[i];
#pragma unroll
            for (int r4 = 0; r4 < 4; ++r4) {
                float4 w = *(const float4*)(wr + r4 * 4);
#pragma unroll
                for (int j = 0; j < 4; ++j) {
                    int r = r4 * 4 + j;
                    float wv = (j == 0) ? w.x : (j == 1) ? w.y : (j == 2) ? w.z : w.w;
                    acc[r][0] = fmaf(x.x, wv, acc[r][0]);
                    acc[r][1] = fmaf(x.y, wv, acc[r][1]);
                    acc[r][2] = fmaf(x.z, wv, acc[r][2]);
                    acc[r][3] = fmaf(x.w, wv, acc[r][3]);
                }
            }
        }
#pragma unroll
        for (int i = 0; i < 4; ++i) xa[i] = xn[i];
    }

    // K-reduce: waves 1..3 dump, wave 0 adds + bias + relu + store
    if (kq > 0) {
#pragma unroll
        for (int r = 0; r < 16; ++r)
            *(float4*)&red[kq - 1][r][lane * 4] =
                make_float4(acc[r][0], acc[r][1], acc[r][2], acc[r][3]);
    }
    __syncthreads();
    if (kq == 0) {
        float v[16][4];
#pragma unroll
        for (int r = 0; r < 16; ++r) {
            float4 s0 = *(float4*)&red[0][r][lane * 4];
            float4 s1 = *(float4*)&red[1][r][lane * 4];
            float4 s2 = *(float4*)&red[2][r][lane * 4];
            float bb = bias[row0 + r];
            float a0 = acc[r][0] + s0.x + s1.x + s2.x + bb;
            float a1 = acc[r][1] + s0.y + s1.y + s2.y + bb;
            float a2 = acc[r][2] + s0.z + s1.z + s2.z + bb;
            float a3 = acc[r][3] + s0.w + s1.w + s2.w + bb;
            v[r][0] = a0 > 0.f ? a0 : 0.f;
            v[r][1] = a1 > 0.f ? a1 : 0.f;
            v[r][2] = a2 > 0.f ? a2 : 0.f;
            v[r][3] = a3 > 0.f ? a3 : 0.f;
        }
#pragma unroll
        for (int q = 0; q < 4; ++q) {
            float* op = Cout + (size_t)(px0 + lane * 4 + q) * 64 + row0;
#pragma unroll
            for (int r4 = 0; r4 < 4; ++r4)
                *(float4*)(op + r4 * 4) = make_float4(v[r4*4+0][q], v[r4*4+1][q],
                                                      v[r4*4+2][q], v[r4*4+3][q]);
        }
    }
}

// ---------------- head: add feat2-up, wo conv, softmax, argmax -> prb/seg ---
__global__ __launch_bounds__(256) void head_kernel(const float* __restrict__ wo,
                                                   const float* __restrict__ bo,
                                                   float* __restrict__ ws) {
    __shared__ float swo[NK * 64];
    __shared__ float sbo[NK];
    for (int i = threadIdx.x; i < NK * 64; i += 256) swo[i] = wo[i];
    if (threadIdx.x < NK) sbo[threadIdx.x] = bo[threadIdx.x];
    __syncthreads();

    int p  = blockIdx.x * 256 + threadIdx.x;   // 0..19199
    int b  = p / P1;
    int pb = p % P1;
    int y  = pb / W1p, x = pb % W1p;
    int qp = (y >> 1) * W2p + (x >> 1);
    const float* c1p = ws + WS_C1 + ((size_t)b * P1 + pb) * 64;
    const float* f2p = ws + WS_F2 + ((size_t)b * P2 + qp) * 64;

    float ok[NK];
#pragma unroll
    for (int k = 0; k < NK; ++k) ok[k] = sbo[k];
#pragma unroll
    for (int o4 = 0; o4 < 16; ++o4) {
        float4 c1q = *(const float4*)(c1p + o4 * 4);
        float4 f2q = *(const float4*)(f2p + o4 * 4);
        float co[4] = { c1q.x + f2q.x, c1q.y + f2q.y, c1q.z + f2q.z, c1q.w + f2q.w };
#pragma unroll
        for (int j = 0; j < 4; ++j) {
            int o = o4 * 4 + j;
#pragma unroll
            for (int k = 0; k < NK; ++k) ok[k] = fmaf(co[j], swo[k * 64 + o], ok[k]);
        }
    }
    float m = 0.f;
#pragma unroll
    for (int k = 0; k < NK; ++k) {
        ok[k] = ok[k] > 0.f ? ok[k] : 0.f;          // relu(out)
        if (ok[k] > m) m = ok[k];
    }
    float e[NK], sum = 0.f;
#pragma unroll
    for (int k = 0; k < NK; ++k) { e[k] = expf(ok[k] - m); sum += e[k]; }
    float inv = 1.f / sum;
    int arg = 0; float best = ok[0];
#pragma unroll
    for (int k = 1; k < NK; ++k) { if (ok[k] > best) { best = ok[k]; arg = k; } }

    float* pr = ws + WS_PRB + (size_t)p * 12;
#pragma unroll
    for (int k = 0; k < NK; ++k) pr[k] = e[k] * inv;
    pr[11] = (float)arg;
    ((int*)(ws + WS_SEG))[p] = arg;
}

// ---------------- upsample 8x: pure streaming replicate-store ----------------
__global__ __launch_bounds__(256) void upsample_kernel(const float* __restrict__ ws,
                                                       float* __restrict__ out) {
    const float* prb = ws + WS_PRB;
    unsigned total4 = (unsigned)((SEG_OFF + (size_t)NB * PLANE) / 4);  // 3,686,400
    unsigned step = gridDim.x * 256;
    for (unsigned i4 = blockIdx.x * 256 + threadIdx.x; i4 < total4; i4 += step) {
        unsigned f = i4 * 4;
        float v;
        if (f < (unsigned)SEG_OFF) {
            unsigned plane = f / (unsigned)PLANE;      // 0..43
            unsigned r = f - plane * (unsigned)PLANE;
            unsigned b = plane / NK, k = plane - b * NK;
            unsigned y = r / WOp, x = r - y * WOp;
            unsigned p = b * P1 + (y >> 3) * W1p + (x >> 3);
            v = prb[p * 12 + k];
        } else {
            unsigned g = f - (unsigned)SEG_OFF;
            unsigned b = g / (unsigned)PLANE;
            unsigned r = g - b * (unsigned)PLANE;
            unsigned y = r / WOp, x = r - y * WOp;
            unsigned p = b * P1 + (y >> 3) * W1p + (x >> 3);
            v = prb[p * 12 + 11];
        }
        *(float4*)(out + f) = make_float4(v, v, v, v);
    }
}

// ---------------- bbox: per-(batch,class) min/max/count over 60x80 seg ------
__global__ __launch_bounds__(256) void bbx_kernel(const float* __restrict__ ws,
                                                  float* __restrict__ out) {
    __shared__ int cnt[10], xmn[10], xmx[10], ymn[10], ymx[10];
    int b = blockIdx.x;
    int t = threadIdx.x;
    if (t < 10) { cnt[t] = 0; xmn[t] = 1 << 30; xmx[t] = -1; ymn[t] = 1 << 30; ymx[t] = -1; }
    __syncthreads();
    const int* seg = (const int*)(ws + WS_SEG) + b * P1;
    for (int p = t; p < P1; p += 256) {
        int s = seg[p];
        if (s >= 1 && s <= 9) {
            int y = p / W1p, x = p % W1p;
            atomicAdd(&cnt[s], 1);
            atomicMin(&xmn[s], x); atomicMax(&xmx[s], x);
            atomicMin(&ymn[s], y); atomicMax(&ymx[s], y);
        }
    }
    __syncthreads();
    if (t < 9) {
        int c = t + 1;
        bool valid = cnt[c] * 64 >= 500;    // upsampled count = 64*count
        float r[6];
        if (valid) {
            r[0] = (float)b;
            r[1] = (float)(xmn[c] * 8);
            r[2] = (float)(ymn[c] * 8);
            r[3] = (float)(xmx[c] * 8 + 7);
            r[4] = (float)(ymx[c] * 8 + 7);
            r[5] = (float)c;
        } else {
            for (int i = 0; i < 6; ++i) r[i] = -1.f;
        }
        float* row = out + BBX_OFF + (size_t)(b * 9 + t) * 6;
        for (int i = 0; i < 6; ++i) row[i] = r[i];
    }
}

extern "C" void kernel_launch(void* const* d_in, const int* in_sizes, int n_in,
                              void* d_out, int out_size, void* d_ws, size_t ws_size,
                              hipStream_t stream) {
    const float* f1 = (const float*)d_in[0];
    const float* f2 = (const float*)d_in[1];
    const float* w1 = (const float*)d_in[2];
    const float* b1 = (const float*)d_in[3];
    const float* w2 = (const float*)d_in[4];
    const float* b2 = (const float*)d_in[5];
    const float* wo = (const float*)d_in[6];
    const float* bo = (const float*)d_in[7];
    float* ws  = (float*)d_ws;
    float* out = (float*)d_out;

    transpose_w<<<128, 256, 0, stream>>>(w1, w2, ws);
    conv_krg<<<384, 256, 0, stream>>>(f1, f2, ws + WS_WT1, ws + WS_WT2,
                                      b1, b2, ws + WS_C1, ws + WS_F2);
    head_kernel<<<75, 256, 0, stream>>>(wo, bo, ws);
    upsample_kernel<<<2048, 256, 0, stream>>>(ws, out);
    bbx_kernel<<<NB, 256, 0, stream>>>(ws, out);
}

// Round 10
// 65.894 us; speedup vs baseline: 2.7875x; 1.0372x over previous
//
#include <hip/hip_runtime.h>
#include <math.h>

#define NB   4
#define CIN  512
#define HID  64
#define NK   11     // NUM_CLASSES+1
#define H1   60
#define W1p  80
#define P1   4800
#define H2   30
#define W2p  40
#define P2   1200
#define HO   480
#define WOp  640
#define NP1  (NB*P1)    // 19200
#define NP2  (NB*P2)    // 4800
#define PLANE ((size_t)HO*WOp)                  // 307200
#define SEG_OFF ((size_t)NB*NK*PLANE)           // 13,516,800
#define BBX_OFF (SEG_OFF + (size_t)NB*PLANE)    // 14,745,600

// ws layout in floats
#define WS_WT1 0
#define WS_WT2 32768
#define WS_C1  65536                            // 19200*64 = 1,228,800
#define WS_F2  (WS_C1 + NP1*64)                 // 4800*64  =   307,200
#define WS_PRB (WS_F2 + NP2*64)                 // 19200*12 =   230,400
#define WS_SEG (WS_PRB + NP1*12)                // 19200 ints

// ---------------- transpose weights: wT[c*64+o] = w[o*512+c] ----------------
__global__ __launch_bounds__(256) void transpose_w(const float* __restrict__ w1,
                                                   const float* __restrict__ w2,
                                                   float* __restrict__ ws) {
    int i = blockIdx.x * 256 + threadIdx.x;   // 0..32767
    if (i >= HID * CIN) return;
    int o = i >> 9;           // /512
    int c = i & 511;
    ws[WS_WT1 + c * HID + o] = w1[i];
    ws[WS_WT2 + c * HID + o] = w2[i];
}

// ---------------- conv1x1 v10: LDS weights + deep x ping-pong ---------------
// Diagnosis r9: per-wave latency-bound -- w loads issued in-iteration with
// ~300-600cy latency stall every 512cy compute group (x was prefetched, w
// NEVER was). Fix: (1) stage this block's weight slice (512ch x 8 rows =
// 16KB) in LDS once; loop reads are ~120cy uniform ds_read_b128, hidden by
// 3-way wave TLP. (2) x: two 8-ch float4 reg buffers, ping-pong, loads
// issued one full 512cy compute block before use (no reg-copy movs).
// (3) 768 blocks (= 96 tiles x 8 row-groups) = 3 blocks/CU exact; acc[8][4]
// keeps VGPR ~140 so all 12 waves/CU resident. XCD swizzle: block D ->
// L=(D&7)*96+(D>>3): each tile's 8 rg-siblings land on one XCD => X re-reads
// are same-L2 hits. Waves = 4 disjoint K-quarters, LDS tree-reduced.
__global__ __launch_bounds__(256) void conv_v10(const float* __restrict__ f1,
                                                const float* __restrict__ f2,
                                                const float* __restrict__ wt1,
                                                const float* __restrict__ wt2,
                                                const float* __restrict__ b1v,
                                                const float* __restrict__ b2v,
                                                float* __restrict__ c1o,
                                                float* __restrict__ f2o) {
    __shared__ float wlds[CIN * 8];     // 16KB: [c][8 rows of this rg]
    __shared__ float red[3][8][256];    // 24KB: kq-reduce buffers
    int D = blockIdx.x;
    int L = (D & 7) * 96 + (D >> 3);    // bijective; siblings of a tile share an XCD
    int tile = L >> 3;
    int rg   = L & 7;
    int row0 = rg << 3;

    const float* X; const float* wT; const float* bias; float* Cout;
    int P, px0;
    if (tile < 76) {                    // f1: 4 batches x 19 tiles (tail overlaps)
        int b = tile / 19; int ti = tile % 19;
        px0 = ti * 256; if (px0 > P1 - 256) px0 = P1 - 256;
        X = f1 + (size_t)b * CIN * P1;  P = P1;  wT = wt1;  bias = b1v;
        Cout = c1o + (size_t)b * P1 * 64;
    } else {                            // f2: 4 batches x 5 tiles (tail overlaps)
        int u = tile - 76; int b = u / 5; int ti = u % 5;
        px0 = ti * 256; if (px0 > P2 - 256) px0 = P2 - 256;
        X = f2 + (size_t)b * CIN * P2;  P = P2;  wT = wt2;  bias = b2v;
        Cout = f2o + (size_t)b * P2 * 64;
    }

    // ---- stage weights: 512 ch x 8 rows -> LDS (one-time) ----
    {
        int t = threadIdx.x;
        int c2 = t >> 1, part = (t & 1) * 4;
#pragma unroll
        for (int i = 0; i < 4; ++i) {
            int c = c2 + i * 128;
            float4 w = *(const float4*)(wT + (size_t)c * 64 + row0 + part);
            *(float4*)&wlds[c * 8 + part] = w;
        }
    }
    __syncthreads();

    int lane  = threadIdx.x & 63;
    int kq    = threadIdx.x >> 6;                // 0..3, disjoint 128-ch quarter
    int cbase = kq << 7;

    const float* Xp = X + (size_t)cbase * P + px0 + lane * 4;

    float acc[8][4];
#pragma unroll
    for (int r = 0; r < 8; ++r)
#pragma unroll
        for (int q = 0; q < 4; ++q) acc[r][q] = 0.f;

    float4 xA[8], xB[8];

    // one 8-channel compute block: 256 FMA insts, w read uniform from LDS
    auto comp8 = [&](const float4* xb, int cq) {
#pragma unroll
        for (int i = 0; i < 8; ++i) {
            const float* wq = wlds + (size_t)(cbase + cq + i) * 8;
            float4 w0 = *(const float4*)(wq);
            float4 w1 = *(const float4*)(wq + 4);
            float4 x  = xb[i];
#pragma unroll
            for (int j = 0; j < 4; ++j) {
                float wv0 = (j == 0) ? w0.x : (j == 1) ? w0.y : (j == 2) ? w0.z : w0.w;
                float wv1 = (j == 0) ? w1.x : (j == 1) ? w1.y : (j == 2) ? w1.z : w1.w;
                acc[j][0]     = fmaf(x.x, wv0, acc[j][0]);
                acc[j][1]     = fmaf(x.y, wv0, acc[j][1]);
                acc[j][2]     = fmaf(x.z, wv0, acc[j][2]);
                acc[j][3]     = fmaf(x.w, wv0, acc[j][3]);
                acc[j + 4][0] = fmaf(x.x, wv1, acc[j + 4][0]);
                acc[j + 4][1] = fmaf(x.y, wv1, acc[j + 4][1]);
                acc[j + 4][2] = fmaf(x.z, wv1, acc[j + 4][2]);
                acc[j + 4][3] = fmaf(x.w, wv1, acc[j + 4][3]);
            }
        }
    };

    // prologue: ch 0..7 into A
#pragma unroll
    for (int i = 0; i < 8; ++i) xA[i] = *(const float4*)(Xp + (size_t)i * P);

    for (int it = 0; it < 8; ++it) {
        int c0 = it * 16;
        // issue loads for ch c0+8..c0+15 (used one 512cy block later)
#pragma unroll
        for (int i = 0; i < 8; ++i)
            xB[i] = *(const float4*)(Xp + (size_t)(c0 + 8 + i) * P);
        comp8(xA, c0);
        if (it < 7) {
#pragma unroll
            for (int i = 0; i < 8; ++i)
                xA[i] = *(const float4*)(Xp + (size_t)(c0 + 16 + i) * P);
        }
        comp8(xB, c0 + 8);
    }

    // ---- kq tree-reduce + bias + relu + store (wave 0) ----
    if (kq > 0) {
#pragma unroll
        for (int r = 0; r < 8; ++r)
            *(float4*)&red[kq - 1][r][lane * 4] =
                make_float4(acc[r][0], acc[r][1], acc[r][2], acc[r][3]);
    }
    __syncthreads();
    if (kq == 0) {
        float v[8][4];
#pragma unroll
        for (int r = 0; r < 8; ++r) {
            float4 s0 = *(float4*)&red[0][r][lane * 4];
            float4 s1 = *(float4*)&red[1][r][lane * 4];
            float4 s2 = *(float4*)&red[2][r][lane * 4];
            float bb = bias[row0 + r];
            float a0 = acc[r][0] + s0.x + s1.x + s2.x + bb;
            float a1 = acc[r][1] + s0.y + s1.y + s2.y + bb;
            float a2 = acc[r][2] + s0.z + s1.z + s2.z + bb;
            float a3 = acc[r][3] + s0.w + s1.w + s2.w + bb;
            v[r][0] = a0 > 0.f ? a0 : 0.f;
            v[r][1] = a1 > 0.f ? a1 : 0.f;
            v[r][2] = a2 > 0.f ? a2 : 0.f;
            v[r][3] = a3 > 0.f ? a3 : 0.f;
        }
#pragma unroll
        for (int q = 0; q < 4; ++q) {
            float* op = Cout + (size_t)(px0 + lane * 4 + q) * 64 + row0;
            *(float4*)(op)     = make_float4(v[0][q], v[1][q], v[2][q], v[3][q]);
            *(float4*)(op + 4) = make_float4(v[4][q], v[5][q], v[6][q], v[7][q]);
        }
    }
}

// ---------------- head: add feat2-up, wo conv, softmax, argmax -> prb/seg ---
__global__ __launch_bounds__(256) void head_kernel(const float* __restrict__ wo,
                                                   const float* __restrict__ bo,
                                                   float* __restrict__ ws) {
    __shared__ float swo[NK * 64];
    __shared__ float sbo[NK];
    for (int i = threadIdx.x; i < NK * 64; i += 256) swo[i] = wo[i];
    if (threadIdx.x < NK) sbo[threadIdx.x] = bo[threadIdx.x];
    __syncthreads();

    int p  = blockIdx.x * 256 + threadIdx.x;   // 0..19199
    int b  = p / P1;
    int pb = p % P1;
    int y  = pb / W1p, x = pb % W1p;
    int qp = (y >> 1) * W2p + (x >> 1);
    const float* c1p = ws + WS_C1 + ((size_t)b * P1 + pb) * 64;
    const float* f2p = ws + WS_F2 + ((size_t)b * P2 + qp) * 64;

    float ok[NK];
#pragma unroll
    for (int k = 0; k < NK; ++k) ok[k] = sbo[k];
#pragma unroll
    for (int o4 = 0; o4 < 16; ++o4) {
        float4 c1q = *(const float4*)(c1p + o4 * 4);
        float4 f2q = *(const float4*)(f2p + o4 * 4);
        float co[4] = { c1q.x + f2q.x, c1q.y + f2q.y, c1q.z + f2q.z, c1q.w + f2q.w };
#pragma unroll
        for (int j = 0; j < 4; ++j) {
            int o = o4 * 4 + j;
#pragma unroll
            for (int k = 0; k < NK; ++k) ok[k] = fmaf(co[j], swo[k * 64 + o], ok[k]);
        }
    }
    float m = 0.f;
#pragma unroll
    for (int k = 0; k < NK; ++k) {
        ok[k] = ok[k] > 0.f ? ok[k] : 0.f;          // relu(out)
        if (ok[k] > m) m = ok[k];
    }
    float e[NK], sum = 0.f;
#pragma unroll
    for (int k = 0; k < NK; ++k) { e[k] = expf(ok[k] - m); sum += e[k]; }
    float inv = 1.f / sum;
    int arg = 0; float best = ok[0];
#pragma unroll
    for (int k = 1; k < NK; ++k) { if (ok[k] > best) { best = ok[k]; arg = k; } }

    float* pr = ws + WS_PRB + (size_t)p * 12;
#pragma unroll
    for (int k = 0; k < NK; ++k) pr[k] = e[k] * inv;
    pr[11] = (float)arg;
    ((int*)(ws + WS_SEG))[p] = arg;
}

// ---------------- upsample 8x: pure streaming replicate-store ----------------
__global__ __launch_bounds__(256) void upsample_kernel(const float* __restrict__ ws,
                                                       float* __restrict__ out) {
    const float* prb = ws + WS_PRB;
    unsigned total4 = (unsigned)((SEG_OFF + (size_t)NB * PLANE) / 4);  // 3,686,400
    unsigned step = gridDim.x * 256;
    for (unsigned i4 = blockIdx.x * 256 + threadIdx.x; i4 < total4; i4 += step) {
        unsigned f = i4 * 4;
        float v;
        if (f < (unsigned)SEG_OFF) {
            unsigned plane = f / (unsigned)PLANE;      // 0..43
            unsigned r = f - plane * (unsigned)PLANE;
            unsigned b = plane / NK, k = plane - b * NK;
            unsigned y = r / WOp, x = r - y * WOp;
            unsigned p = b * P1 + (y >> 3) * W1p + (x >> 3);
            v = prb[p * 12 + k];
        } else {
            unsigned g = f - (unsigned)SEG_OFF;
            unsigned b = g / (unsigned)PLANE;
            unsigned r = g - b * (unsigned)PLANE;
            unsigned y = r / WOp, x = r - y * WOp;
            unsigned p = b * P1 + (y >> 3) * W1p + (x >> 3);
            v = prb[p * 12 + 11];
        }
        *(float4*)(out + f) = make_float4(v, v, v, v);
    }
}

// ---------------- bbox: per-(batch,class) min/max/count over 60x80 seg ------
__global__ __launch_bounds__(256) void bbx_kernel(const float* __restrict__ ws,
                                                  float* __restrict__ out) {
    __shared__ int cnt[10], xmn[10], xmx[10], ymn[10], ymx[10];
    int b = blockIdx.x;
    int t = threadIdx.x;
    if (t < 10) { cnt[t] = 0; xmn[t] = 1 << 30; xmx[t] = -1; ymn[t] = 1 << 30; ymx[t] = -1; }
    __syncthreads();
    const int* seg = (const int*)(ws + WS_SEG) + b * P1;
    for (int p = t; p < P1; p += 256) {
        int s = seg[p];
        if (s >= 1 && s <= 9) {
            int y = p / W1p, x = p % W1p;
            atomicAdd(&cnt[s], 1);
            atomicMin(&xmn[s], x); atomicMax(&xmx[s], x);
            atomicMin(&ymn[s], y); atomicMax(&ymx[s], y);
        }
    }
    __syncthreads();
    if (t < 9) {
        int c = t + 1;
        bool valid = cnt[c] * 64 >= 500;    // upsampled count = 64*count
        float r[6];
        if (valid) {
            r[0] = (float)b;
            r[1] = (float)(xmn[c] * 8);
            r[2] = (float)(ymn[c] * 8);
            r[3] = (float)(xmx[c] * 8 + 7);
            r[4] = (float)(ymx[c] * 8 + 7);
            r[5] = (float)c;
        } else {
            for (int i = 0; i < 6; ++i) r[i] = -1.f;
        }
        float* row = out + BBX_OFF + (size_t)(b * 9 + t) * 6;
        for (int i = 0; i < 6; ++i) row[i] = r[i];
    }
}

extern "C" void kernel_launch(void* const* d_in, const int* in_sizes, int n_in,
                              void* d_out, int out_size, void* d_ws, size_t ws_size,
                              hipStream_t stream) {
    const float* f1 = (const float*)d_in[0];
    const float* f2 = (const float*)d_in[1];
    const float* w1 = (const float*)d_in[2];
    const float* b1 = (const float*)d_in[3];
    const float* w2 = (const float*)d_in[4];
    const float* b2 = (const float*)d_in[5];
    const float* wo = (const float*)d_in[6];
    const float* bo = (const float*)d_in[7];
    float* ws  = (float*)d_ws;
    float* out = (float*)d_out;

    transpose_w<<<128, 256, 0, stream>>>(w1, w2, ws);
    conv_v10<<<768, 256, 0, stream>>>(f1, f2, ws + WS_WT1, ws + WS_WT2,
                                      b1, b2, ws + WS_C1, ws + WS_F2);
    head_kernel<<<75, 256, 0, stream>>>(wo, bo, ws);
    upsample_kernel<<<2048, 256, 0, stream>>>(ws, out);
    bbx_kernel<<<NB, 256, 0, stream>>>(ws, out);
}